// Round 1
// baseline (846.622 us; speedup 1.0000x reference)
//
#include <hip/hip_runtime.h>
#include <hip/hip_bf16.h>

#define B_ 16
#define T_ 32
#define D_ 4096
#define H_ 32
#define HD_ 128
#define MAXS_ 2048

typedef __hip_bfloat16 bf16;
typedef __attribute__((ext_vector_type(8))) short bf16x8;
typedef __attribute__((ext_vector_type(4))) float f32x4;

static __device__ __forceinline__ short f2b(float f) {
    bf16 h = __float2bfloat16(f);
    return *reinterpret_cast<short*>(&h);
}

// ---------------- GEMM: C(f32) = A(f32->bf16) @ W(f32->bf16), tile 128x128, BK=32 ----------------
// A: M x K row-major (f32), W: K x N row-major (f32). Grid: (N/128, M/128, 3) selecting wq/wk/wv.
__global__ __launch_bounds__(256) void gemm_qkv(const float* __restrict__ x,
        const float* __restrict__ wq, const float* __restrict__ wk, const float* __restrict__ wv,
        float* __restrict__ outbase) {
    const int N = D_, K = D_;
    const float* Bw = (blockIdx.z == 0) ? wq : (blockIdx.z == 1) ? wk : wv;
    float* C = outbase + (size_t)blockIdx.z * (B_ * T_) * D_;
    __shared__ bf16 As[128][40];   // [m][k], pad to 40 (80B stride: 16B-aligned, 2-way max conflict)
    __shared__ bf16 Bs[128][40];   // [n][k] (transposed)
    const int tid = threadIdx.x;
    const int lane = tid & 63, wave = tid >> 6;
    const int wr = wave >> 1, wc = wave & 1;
    const int lg = lane >> 4, li = lane & 15;
    const int row0 = blockIdx.y * 128, col0 = blockIdx.x * 128;
    f32x4 acc[4][4];
    for (int i = 0; i < 4; ++i) for (int j = 0; j < 4; ++j) for (int r = 0; r < 4; ++r) acc[i][j][r] = 0.f;

    for (int k0 = 0; k0 < K; k0 += 32) {
        // stage A tile 128x32
        #pragma unroll
        for (int r = 0; r < 4; ++r) {
            int row = (tid >> 3) + 32 * r;
            int kk = (tid & 7) * 4;
            float4 v = *(const float4*)(&x[(size_t)(row0 + row) * K + k0 + kk]);
            As[row][kk + 0] = __float2bfloat16(v.x);
            As[row][kk + 1] = __float2bfloat16(v.y);
            As[row][kk + 2] = __float2bfloat16(v.z);
            As[row][kk + 3] = __float2bfloat16(v.w);
        }
        // stage B tile 32x128, transposed into Bs[n][k]
        #pragma unroll
        for (int r = 0; r < 4; ++r) {
            int kk = (tid >> 5) + 8 * r;
            int nn = (tid & 31) * 4;
            float4 v = *(const float4*)(&Bw[(size_t)(k0 + kk) * N + col0 + nn]);
            Bs[nn + 0][kk] = __float2bfloat16(v.x);
            Bs[nn + 1][kk] = __float2bfloat16(v.y);
            Bs[nn + 2][kk] = __float2bfloat16(v.z);
            Bs[nn + 3][kk] = __float2bfloat16(v.w);
        }
        __syncthreads();
        bf16x8 af[4], bfr[4];
        #pragma unroll
        for (int i = 0; i < 4; ++i) af[i] = *(const bf16x8*)(&As[wr * 64 + i * 16 + li][lg * 8]);
        #pragma unroll
        for (int j = 0; j < 4; ++j) bfr[j] = *(const bf16x8*)(&Bs[wc * 64 + j * 16 + li][lg * 8]);
        #pragma unroll
        for (int i = 0; i < 4; ++i)
            #pragma unroll
            for (int j = 0; j < 4; ++j)
                acc[i][j] = __builtin_amdgcn_mfma_f32_16x16x32_bf16(af[i], bfr[j], acc[i][j], 0, 0, 0);
        __syncthreads();
    }
    #pragma unroll
    for (int i = 0; i < 4; ++i)
        for (int j = 0; j < 4; ++j)
            for (int r = 0; r < 4; ++r) {
                int row = row0 + wr * 64 + i * 16 + lg * 4 + r;
                int col = col0 + wc * 64 + j * 16 + li;
                C[(size_t)row * N + col] = acc[i][j][r];
            }
}

// ---------------- GEMM: C(f32) = A(bf16) @ W(f32->bf16) ----------------
__global__ __launch_bounds__(256) void gemm_bf16A(const bf16* __restrict__ A,
        const float* __restrict__ Bw, float* __restrict__ C) {
    const int N = D_, K = D_;
    __shared__ bf16 As[128][40];
    __shared__ bf16 Bs[128][40];
    const int tid = threadIdx.x;
    const int lane = tid & 63, wave = tid >> 6;
    const int wr = wave >> 1, wc = wave & 1;
    const int lg = lane >> 4, li = lane & 15;
    const int row0 = blockIdx.y * 128, col0 = blockIdx.x * 128;
    f32x4 acc[4][4];
    for (int i = 0; i < 4; ++i) for (int j = 0; j < 4; ++j) for (int r = 0; r < 4; ++r) acc[i][j][r] = 0.f;

    for (int k0 = 0; k0 < K; k0 += 32) {
        #pragma unroll
        for (int r = 0; r < 2; ++r) {
            int row = (tid >> 2) + 64 * r;
            int kk = (tid & 3) * 8;
            *(uint4*)(&As[row][kk]) = *(const uint4*)(&A[(size_t)(row0 + row) * K + k0 + kk]);
        }
        #pragma unroll
        for (int r = 0; r < 4; ++r) {
            int kk = (tid >> 5) + 8 * r;
            int nn = (tid & 31) * 4;
            float4 v = *(const float4*)(&Bw[(size_t)(k0 + kk) * N + col0 + nn]);
            Bs[nn + 0][kk] = __float2bfloat16(v.x);
            Bs[nn + 1][kk] = __float2bfloat16(v.y);
            Bs[nn + 2][kk] = __float2bfloat16(v.z);
            Bs[nn + 3][kk] = __float2bfloat16(v.w);
        }
        __syncthreads();
        bf16x8 af[4], bfr[4];
        #pragma unroll
        for (int i = 0; i < 4; ++i) af[i] = *(const bf16x8*)(&As[wr * 64 + i * 16 + li][lg * 8]);
        #pragma unroll
        for (int j = 0; j < 4; ++j) bfr[j] = *(const bf16x8*)(&Bs[wc * 64 + j * 16 + li][lg * 8]);
        #pragma unroll
        for (int i = 0; i < 4; ++i)
            #pragma unroll
            for (int j = 0; j < 4; ++j)
                acc[i][j] = __builtin_amdgcn_mfma_f32_16x16x32_bf16(af[i], bfr[j], acc[i][j], 0, 0, 0);
        __syncthreads();
    }
    #pragma unroll
    for (int i = 0; i < 4; ++i)
        for (int j = 0; j < 4; ++j)
            for (int r = 0; r < 4; ++r) {
                int row = row0 + wr * 64 + i * 16 + lg * 4 + r;
                int col = col0 + wc * 64 + j * 16 + li;
                C[(size_t)row * N + col] = acc[i][j][r];
            }
}

// ---------------- RoPE (positions 0..T-1, theta_i = 10000^(-i/32) per reference) + cast ----------------
__global__ void rope_cast(const float* __restrict__ qkv, bf16* __restrict__ qb,
                          bf16* __restrict__ kb, bf16* __restrict__ vb) {
    int idx = blockIdx.x * blockDim.x + threadIdx.x;  // pair index, [0, B*T*H*64)
    int i = idx & 63;
    int t = (idx >> 11) & (T_ - 1);
    size_t base = ((size_t)(idx >> 6)) * 2 + ((size_t)0);  // == element index of pair start
    base = (size_t)(idx) * 2 - i * 2 + 2 * i;              // simplify: element base
    base = (size_t)idx * 2;                                // contiguous pairs: works since layout is [b][t][h][hd]
    const float* q = qkv;
    const float* k = qkv + (size_t)B_ * T_ * D_;
    const float* v = qkv + (size_t)2 * B_ * T_ * D_;
    // reference: theta = 10000^(-2*arange(0,128,2)/128) = 10000^(-i/32)
    float theta = exp2f(-(float)i * 0.41524101186092787f);  // i * log2(10000)/32
    float ang = (float)t * theta;
    float s, c;
    sincosf(ang, &s, &c);
    float q0 = q[base], q1 = q[base + 1];
    qb[base]     = __float2bfloat16(q0 * c - q1 * s);
    qb[base + 1] = __float2bfloat16(q1 * c + q0 * s);
    float k0 = k[base], k1 = k[base + 1];
    kb[base]     = __float2bfloat16(k0 * c - k1 * s);
    kb[base + 1] = __float2bfloat16(k1 * c + k0 * s);
    vb[base]     = __float2bfloat16(v[base]);
    vb[base + 1] = __float2bfloat16(v[base + 1]);
}

// ---------------- Flash attention: 1 block per (b,h), 4 waves split KV chunks of 32 ----------------
__global__ __launch_bounds__(256) void attn(const bf16* __restrict__ qb,
        const bf16* __restrict__ kb, const bf16* __restrict__ vb,
        const float* __restrict__ kc, const float* __restrict__ vc,
        const int* __restrict__ spp, bf16* __restrict__ ob) {
    const int bh = blockIdx.x;
    const int b = bh >> 5, h = bh & 31;
    const int sp = *spp;
    const int L = sp + T_;
    const int tid = threadIdx.x, lane = tid & 63, wave = tid >> 6;
    const int lg = lane >> 4, li = lane & 15;
    __shared__ bf16 Plds[4][32][40];
    __shared__ float Osh[32][128];
    __shared__ float msh[4][32], lsh[4][32], ltot[32];

    // Q fragments (rows 16*rt+li, dims kk*32 + lg*8 + j)
    bf16x8 qf[2][4];
    #pragma unroll
    for (int rt = 0; rt < 2; ++rt)
        #pragma unroll
        for (int kk = 0; kk < 4; ++kk)
            qf[rt][kk] = *(const bf16x8*)(&qb[((size_t)(b * T_ + rt * 16 + li) * H_ + h) * HD_ + kk * 32 + lg * 8]);

    f32x4 o[2][8];
    float m_r[2][4], l_r[2][4];
    #pragma unroll
    for (int rt = 0; rt < 2; ++rt)
        for (int r = 0; r < 4; ++r) { m_r[rt][r] = -1e30f; l_r[rt][r] = 0.f; }
    #pragma unroll
    for (int rt = 0; rt < 2; ++rt) for (int ht = 0; ht < 8; ++ht) for (int r = 0; r < 4; ++r) o[rt][ht][r] = 0.f;

    const int nch = (L + 31) >> 5;
    for (int c = wave; c < nch; c += 4) {
        const int s0 = c * 32;
        // K fragments: B[d][s] = K[s][d]; lane: s = s0+ct*16+li, d = kk*32+lg*8+j
        bf16x8 kf[2][4];
        #pragma unroll
        for (int ct = 0; ct < 2; ++ct) {
            int s = s0 + ct * 16 + li;
            if (s < sp) {
                const float* kp = &kc[(((size_t)b * MAXS_ + s) * H_ + h) * HD_];
                #pragma unroll
                for (int kk = 0; kk < 4; ++kk) {
                    float4 v0 = *(const float4*)(&kp[kk * 32 + lg * 8]);
                    float4 v1 = *(const float4*)(&kp[kk * 32 + lg * 8 + 4]);
                    bf16x8 f;
                    f[0] = f2b(v0.x); f[1] = f2b(v0.y); f[2] = f2b(v0.z); f[3] = f2b(v0.w);
                    f[4] = f2b(v1.x); f[5] = f2b(v1.y); f[6] = f2b(v1.z); f[7] = f2b(v1.w);
                    kf[ct][kk] = f;
                }
            } else if (s < L) {
                const bf16* kp = &kb[((size_t)(b * T_ + s - sp) * H_ + h) * HD_];
                #pragma unroll
                for (int kk = 0; kk < 4; ++kk)
                    kf[ct][kk] = *(const bf16x8*)(&kp[kk * 32 + lg * 8]);
            } else {
                #pragma unroll
                for (int kk = 0; kk < 4; ++kk) {
                    bf16x8 f;
                    #pragma unroll
                    for (int j = 0; j < 8; ++j) f[j] = 0;
                    kf[ct][kk] = f;
                }
            }
        }
        // scores
        f32x4 sc[2][2];
        #pragma unroll
        for (int rt = 0; rt < 2; ++rt)
            #pragma unroll
            for (int ct = 0; ct < 2; ++ct) {
                f32x4 a;
                for (int r = 0; r < 4; ++r) a[r] = 0.f;
                #pragma unroll
                for (int kk = 0; kk < 4; ++kk)
                    a = __builtin_amdgcn_mfma_f32_16x16x32_bf16(qf[rt][kk], kf[ct][kk], a, 0, 0, 0);
                sc[rt][ct] = a;
            }
        const float scale = 0.08838834764831845f;  // 1/sqrt(128)
        // online softmax; D layout: row = 16*rt + 4*lg + r, col = ct*16 + li
        #pragma unroll
        for (int rt = 0; rt < 2; ++rt) {
            #pragma unroll
            for (int r = 0; r < 4; ++r) {
                float x0 = sc[rt][0][r] * scale;
                float x1 = sc[rt][1][r] * scale;
                if (s0 + li >= L) x0 = -1e30f;
                if (s0 + 16 + li >= L) x1 = -1e30f;
                float mx = fmaxf(x0, x1);
                #pragma unroll
                for (int off = 1; off < 16; off <<= 1) mx = fmaxf(mx, __shfl_xor(mx, off, 64));
                float mnew = fmaxf(m_r[rt][r], mx);
                float corr = __expf(m_r[rt][r] - mnew);
                float p0 = __expf(x0 - mnew);
                float p1 = __expf(x1 - mnew);
                float rs = p0 + p1;
                #pragma unroll
                for (int off = 1; off < 16; off <<= 1) rs += __shfl_xor(rs, off, 64);
                m_r[rt][r] = mnew;
                l_r[rt][r] = l_r[rt][r] * corr + rs;
                #pragma unroll
                for (int ht = 0; ht < 8; ++ht) o[rt][ht][r] *= corr;
                Plds[wave][rt * 16 + lg * 4 + r][li]      = __float2bfloat16(p0);
                Plds[wave][rt * 16 + lg * 4 + r][16 + li] = __float2bfloat16(p1);
            }
        }
        // wave-private LDS transpose of P; wave executes in lockstep, just drain LDS
        asm volatile("s_waitcnt lgkmcnt(0)" ::: "memory");
        bf16x8 pf[2];
        pf[0] = *(const bf16x8*)(&Plds[wave][li][lg * 8]);
        pf[1] = *(const bf16x8*)(&Plds[wave][16 + li][lg * 8]);
        // V fragments + PV; B[s][hd]: lane: hd = ht*16+li, s = s0 + lg*8 + j
        #pragma unroll
        for (int ht = 0; ht < 8; ++ht) {
            bf16x8 vf;
            #pragma unroll
            for (int j = 0; j < 8; ++j) {
                int s = s0 + lg * 8 + j;
                if (s < sp) {
                    vf[j] = f2b(vc[(((size_t)b * MAXS_ + s) * H_ + h) * HD_ + ht * 16 + li]);
                } else if (s < L) {
                    vf[j] = *reinterpret_cast<const short*>(&vb[((size_t)(b * T_ + s - sp) * H_ + h) * HD_ + ht * 16 + li]);
                } else {
                    vf[j] = 0;
                }
            }
            #pragma unroll
            for (int rt = 0; rt < 2; ++rt)
                o[rt][ht] = __builtin_amdgcn_mfma_f32_16x16x32_bf16(pf[rt], vf, o[rt][ht], 0, 0, 0);
        }
    }

    // cross-wave combine
    if (li == 0) {
        #pragma unroll
        for (int rt = 0; rt < 2; ++rt)
            for (int r = 0; r < 4; ++r) {
                msh[wave][rt * 16 + lg * 4 + r] = m_r[rt][r];
                lsh[wave][rt * 16 + lg * 4 + r] = l_r[rt][r];
            }
    }
    __syncthreads();
    float corr2[2][4];
    #pragma unroll
    for (int rt = 0; rt < 2; ++rt)
        for (int r = 0; r < 4; ++r) {
            int row = rt * 16 + lg * 4 + r;
            float M = fmaxf(fmaxf(msh[0][row], msh[1][row]), fmaxf(msh[2][row], msh[3][row]));
            corr2[rt][r] = __expf(m_r[rt][r] - M);
        }
    if (tid < 32) {
        int row = tid;
        float M = fmaxf(fmaxf(msh[0][row], msh[1][row]), fmaxf(msh[2][row], msh[3][row]));
        float lt = 0.f;
        #pragma unroll
        for (int w = 0; w < 4; ++w) lt += lsh[w][row] * __expf(msh[w][row] - M);
        ltot[row] = lt;
    }
    for (int w = 0; w < 4; ++w) {
        if (wave == w) {
            #pragma unroll
            for (int rt = 0; rt < 2; ++rt)
                for (int ht = 0; ht < 8; ++ht)
                    for (int r = 0; r < 4; ++r) {
                        int row = rt * 16 + lg * 4 + r, col = ht * 16 + li;
                        float val = o[rt][ht][r] * corr2[rt][r];
                        if (w == 0) Osh[row][col] = val;
                        else Osh[row][col] += val;
                    }
        }
        __syncthreads();
    }
    // write attention output: [b][t][h*HD + col], bf16 for the wo GEMM
    {
        int row = tid >> 3;
        int c0 = (tid & 7) * 16;
        float inv = 1.0f / ltot[row];
        #pragma unroll
        for (int j = 0; j < 16; ++j)
            ob[(size_t)(b * T_ + row) * D_ + h * HD_ + c0 + j] = __float2bfloat16(Osh[row][c0 + j] * inv);
    }
}

extern "C" void kernel_launch(void* const* d_in, const int* in_sizes, int n_in,
                              void* d_out, int out_size, void* d_ws, size_t ws_size,
                              hipStream_t stream) {
    const float* x  = (const float*)d_in[0];
    const float* wq = (const float*)d_in[1];
    const float* wk = (const float*)d_in[2];
    const float* wv = (const float*)d_in[3];
    const float* wo = (const float*)d_in[4];
    const float* kc = (const float*)d_in[5];
    const float* vc = (const float*)d_in[6];
    const int*   sp = (const int*)d_in[7];
    float* out = (float*)d_out;

    char* ws = (char*)d_ws;
    const size_t MT = (size_t)B_ * T_ * D_;  // 2M elements
    float* qkv = (float*)ws;                   // 3*MT f32 (q,k,v pre-rope) = 24 MB
    bf16* qb = (bf16*)(ws + 3 * MT * 4);       // 4 MB each
    bf16* kb = qb + MT;
    bf16* vb = kb + MT;
    bf16* ab = vb + MT;

    gemm_qkv<<<dim3(D_ / 128, (B_ * T_) / 128, 3), 256, 0, stream>>>(x, wq, wk, wv, qkv);
    rope_cast<<<dim3((B_ * T_ * H_ * 64) / 256), 256, 0, stream>>>(qkv, qb, kb, vb);
    attn<<<dim3(B_ * H_), 256, 0, stream>>>(qb, kb, vb, kc, vc, sp, ab);
    gemm_bf16A<<<dim3(D_ / 128, (B_ * T_) / 128, 1), 256, 0, stream>>>(ab, wo, out);
}

// Round 2
// 531.850 us; speedup vs baseline: 1.5918x; 1.5918x over previous
//
#include <hip/hip_runtime.h>
#include <hip/hip_bf16.h>

#define B_ 16
#define T_ 32
#define D_ 4096
#define H_ 32
#define HD_ 128
#define MAXS_ 2048
#define M_ (B_*T_)   // 512 rows

typedef __hip_bfloat16 bf16;
typedef __attribute__((ext_vector_type(8))) short bf16x8;
typedef __attribute__((ext_vector_type(4))) float f32x4;

static __device__ __forceinline__ short f2b(float f) {
    bf16 h = __float2bfloat16(f);
    return *reinterpret_cast<short*>(&h);
}
static __device__ __forceinline__ float b2f(short s) {
    bf16 h;
    *reinterpret_cast<short*>(&h) = s;
    return __bfloat162float(h);
}

// async global->LDS, 16B per lane; LDS dest is wave-uniform base + lane*16
#define GLD16(gsrc, ldst) \
    __builtin_amdgcn_global_load_lds((const __attribute__((address_space(1))) void*)(gsrc), \
        (__attribute__((address_space(3))) void*)(ldst), 16, 0, 0)

// ---------------- x f32 -> bf16 ----------------
__global__ __launch_bounds__(256) void conv_x(const float* __restrict__ x, bf16* __restrict__ xb) {
    int idx = blockIdx.x * 256 + threadIdx.x;   // 8-element unit
    const float4* xf = (const float4*)x;
    float4 a = xf[idx * 2], b = xf[idx * 2 + 1];
    bf16x8 o;
    o[0] = f2b(a.x); o[1] = f2b(a.y); o[2] = f2b(a.z); o[3] = f2b(a.w);
    o[4] = f2b(b.x); o[5] = f2b(b.y); o[6] = f2b(b.z); o[7] = f2b(b.w);
    *(bf16x8*)&xb[(size_t)idx * 8] = o;
}

// ---------------- W [k][n] f32 -> Wt [n][k] bf16, 64x64 LDS tiles ----------------
__global__ __launch_bounds__(256) void transpose_w(const float* __restrict__ wq,
        const float* __restrict__ wk, const float* __restrict__ wv,
        const float* __restrict__ wo, bf16* __restrict__ wt) {
    __shared__ float Ts[64][65];   // +1 pad: banks rotate per row
    const int bz = blockIdx.z;
    const float* W = (bz == 0) ? wq : (bz == 1) ? wk : (bz == 2) ? wv : wo;
    const int n0 = blockIdx.x * 64, k0 = blockIdx.y * 64;
    const int t = threadIdx.x;
    {
        int kk = t >> 4, nn = (t & 15) * 4;
        #pragma unroll
        for (int r = 0; r < 4; ++r) {
            float4 v = *(const float4*)&W[(size_t)(k0 + kk + 16 * r) * D_ + n0 + nn];
            Ts[kk + 16 * r][nn + 0] = v.x;
            Ts[kk + 16 * r][nn + 1] = v.y;
            Ts[kk + 16 * r][nn + 2] = v.z;
            Ts[kk + 16 * r][nn + 3] = v.w;
        }
    }
    __syncthreads();
    bf16* dst = wt + (size_t)bz * D_ * D_;   // row block bz*4096
    const int kg = t & 7, nr = t >> 3;
    #pragma unroll
    for (int r = 0; r < 2; ++r) {
        int n = nr + 32 * r;
        bf16x8 o;
        #pragma unroll
        for (int j = 0; j < 8; ++j) o[j] = f2b(Ts[kg * 8 + j][n]);
        *(bf16x8*)&dst[(size_t)(n0 + n) * D_ + k0 + kg * 8] = o;
    }
}

// ---------------- bf16 GEMM, m97 structure: gload_lds(16B) + XOR-swizzled LDS ----------------
// A: [M][K] bf16 row-major. Bt: [N][K] bf16 (pre-transposed weights). BN=128, BK=32.
// MODE 0: bf16 out, N=12288 split into 3 tensors of [M_][D_] (q,k,v). MODE 1: f32 out [M_][D_].
template<int BM, int MODE>
__global__ __launch_bounds__(256) void gemm_bf16t(const bf16* __restrict__ A,
        const bf16* __restrict__ Bt, void* __restrict__ Cout) {
    constexpr int IM = BM / 32;          // A-frags per wave (wave tile BM/2 x 64)
    constexpr int nA = (BM * 64) / 4096; // gload_lds instrs for A tile
    const int K = D_;
    __shared__ bf16 As[BM * 32];
    __shared__ bf16 Bs[128 * 32];
    const int tid = threadIdx.x, lane = tid & 63, wave = tid >> 6;
    const int wr = wave >> 1, wc = wave & 1;
    const int lg = lane >> 4, li = lane & 15;
    const int row0 = blockIdx.y * BM, col0 = blockIdx.x * 128;
    f32x4 acc[IM][4];
    #pragma unroll
    for (int i = 0; i < IM; ++i)
        #pragma unroll
        for (int j = 0; j < 4; ++j)
            #pragma unroll
            for (int r = 0; r < 4; ++r) acc[i][j][r] = 0.f;

    // precompute swizzle-inverted source offsets (row, kbyte) per gload instr
    const int sw = (li & 3) << 4;
    for (int k0 = 0; k0 < K; k0 += 32) {
        #pragma unroll
        for (int i = 0; i < nA; ++i) {
            int X = (i * 256 + tid) * 16;              // linear LDS byte
            int row = X >> 6;
            int kb = (X & 63) ^ ((row & 3) << 4);      // inverse swizzle on source
            GLD16(A + (size_t)(row0 + row) * K + k0 + (kb >> 1),
                  (char*)As + (i * 256 + wave * 64) * 16);
        }
        #pragma unroll
        for (int i = 0; i < 2; ++i) {
            int X = (i * 256 + tid) * 16;
            int row = X >> 6;
            int kb = (X & 63) ^ ((row & 3) << 4);
            GLD16(Bt + (size_t)(col0 + row) * K + k0 + (kb >> 1),
                  (char*)Bs + (i * 256 + wave * 64) * 16);
        }
        __syncthreads();
        bf16x8 af[IM], bfr[4];
        #pragma unroll
        for (int i = 0; i < IM; ++i) {
            int row = wr * (BM / 2) + i * 16 + li;
            af[i] = *(const bf16x8*)((const char*)As + row * 64 + ((lg * 16) ^ sw));
        }
        #pragma unroll
        for (int j = 0; j < 4; ++j) {
            int row = wc * 64 + j * 16 + li;
            bfr[j] = *(const bf16x8*)((const char*)Bs + row * 64 + ((lg * 16) ^ sw));
        }
        #pragma unroll
        for (int i = 0; i < IM; ++i)
            #pragma unroll
            for (int j = 0; j < 4; ++j)
                acc[i][j] = __builtin_amdgcn_mfma_f32_16x16x32_bf16(af[i], bfr[j], acc[i][j], 0, 0, 0);
        __syncthreads();
    }
    if (MODE == 0) {
        bf16* Ob = (bf16*)Cout + (size_t)(col0 >> 12) * M_ * D_;
        const int lcol0 = col0 & (D_ - 1);
        #pragma unroll
        for (int i = 0; i < IM; ++i)
            for (int j = 0; j < 4; ++j)
                for (int r = 0; r < 4; ++r) {
                    int row = row0 + wr * (BM / 2) + i * 16 + lg * 4 + r;
                    int col = lcol0 + wc * 64 + j * 16 + li;
                    Ob[(size_t)row * D_ + col] = __float2bfloat16(acc[i][j][r]);
                }
    } else {
        float* O = (float*)Cout;
        #pragma unroll
        for (int i = 0; i < IM; ++i)
            for (int j = 0; j < 4; ++j)
                for (int r = 0; r < 4; ++r) {
                    int row = row0 + wr * (BM / 2) + i * 16 + lg * 4 + r;
                    int col = col0 + wc * 64 + j * 16 + li;
                    O[(size_t)row * D_ + col] = acc[i][j][r];
                }
    }
}

// ---------------- RoPE in-place on bf16 q,k (positions 0..T-1, theta_i = 10000^(-i/32)) ----------------
__global__ __launch_bounds__(256) void rope_inplace(bf16* __restrict__ qb, bf16* __restrict__ kb) {
    int idx = blockIdx.x * 256 + threadIdx.x;   // 8-element (4-pair) unit
    size_t e0 = (size_t)idx * 8;
    int hd0 = (int)(e0 & 127);
    int t = (int)((e0 >> 12) & 31);
    bf16x8 q = *(bf16x8*)&qb[e0];
    bf16x8 k = *(bf16x8*)&kb[e0];
    bf16x8 qo, ko;
    #pragma unroll
    for (int p = 0; p < 4; ++p) {
        int i = (hd0 >> 1) + p;
        float theta = exp2f(-(float)i * 0.41524101186092787f);  // log2(10000)/32
        float s, c;
        sincosf((float)t * theta, &s, &c);
        float q0 = b2f(q[2 * p]), q1 = b2f(q[2 * p + 1]);
        qo[2 * p]     = f2b(q0 * c - q1 * s);
        qo[2 * p + 1] = f2b(q1 * c + q0 * s);
        float k0 = b2f(k[2 * p]), k1 = b2f(k[2 * p + 1]);
        ko[2 * p]     = f2b(k0 * c - k1 * s);
        ko[2 * p + 1] = f2b(k1 * c + k0 * s);
    }
    *(bf16x8*)&qb[e0] = qo;
    *(bf16x8*)&kb[e0] = ko;
}

// ---------------- Flash attention: 1 block per (b,h), 4 waves split KV chunks of 32 ----------------
__global__ __launch_bounds__(256) void attn(const bf16* __restrict__ qb,
        const bf16* __restrict__ kb, const bf16* __restrict__ vb,
        const float* __restrict__ kc, const float* __restrict__ vc,
        const int* __restrict__ spp, bf16* __restrict__ ob) {
    const int bh = blockIdx.x;
    const int b = bh >> 5, h = bh & 31;
    const int sp = *spp;
    const int L = sp + T_;
    const int tid = threadIdx.x, lane = tid & 63, wave = tid >> 6;
    const int lg = lane >> 4, li = lane & 15;
    __shared__ bf16 Plds[4][32][40];
    __shared__ float Osh[32][128];
    __shared__ float msh[4][32], lsh[4][32], ltot[32];

    bf16x8 qf[2][4];
    #pragma unroll
    for (int rt = 0; rt < 2; ++rt)
        #pragma unroll
        for (int kk = 0; kk < 4; ++kk)
            qf[rt][kk] = *(const bf16x8*)(&qb[((size_t)(b * T_ + rt * 16 + li) * H_ + h) * HD_ + kk * 32 + lg * 8]);

    f32x4 o[2][8];
    float m_r[2][4], l_r[2][4];
    #pragma unroll
    for (int rt = 0; rt < 2; ++rt)
        for (int r = 0; r < 4; ++r) { m_r[rt][r] = -1e30f; l_r[rt][r] = 0.f; }
    #pragma unroll
    for (int rt = 0; rt < 2; ++rt) for (int ht = 0; ht < 8; ++ht) for (int r = 0; r < 4; ++r) o[rt][ht][r] = 0.f;

    const int nch = (L + 31) >> 5;
    for (int c = wave; c < nch; c += 4) {
        const int s0 = c * 32;
        bf16x8 kf[2][4];
        #pragma unroll
        for (int ct = 0; ct < 2; ++ct) {
            int s = s0 + ct * 16 + li;
            if (s < sp) {
                const float* kp = &kc[(((size_t)b * MAXS_ + s) * H_ + h) * HD_];
                #pragma unroll
                for (int kk = 0; kk < 4; ++kk) {
                    float4 v0 = *(const float4*)(&kp[kk * 32 + lg * 8]);
                    float4 v1 = *(const float4*)(&kp[kk * 32 + lg * 8 + 4]);
                    bf16x8 f;
                    f[0] = f2b(v0.x); f[1] = f2b(v0.y); f[2] = f2b(v0.z); f[3] = f2b(v0.w);
                    f[4] = f2b(v1.x); f[5] = f2b(v1.y); f[6] = f2b(v1.z); f[7] = f2b(v1.w);
                    kf[ct][kk] = f;
                }
            } else if (s < L) {
                const bf16* kp = &kb[((size_t)(b * T_ + s - sp) * H_ + h) * HD_];
                #pragma unroll
                for (int kk = 0; kk < 4; ++kk)
                    kf[ct][kk] = *(const bf16x8*)(&kp[kk * 32 + lg * 8]);
            } else {
                #pragma unroll
                for (int kk = 0; kk < 4; ++kk) {
                    bf16x8 f;
                    #pragma unroll
                    for (int j = 0; j < 8; ++j) f[j] = 0;
                    kf[ct][kk] = f;
                }
            }
        }
        f32x4 sc[2][2];
        #pragma unroll
        for (int rt = 0; rt < 2; ++rt)
            #pragma unroll
            for (int ct = 0; ct < 2; ++ct) {
                f32x4 a;
                for (int r = 0; r < 4; ++r) a[r] = 0.f;
                #pragma unroll
                for (int kk = 0; kk < 4; ++kk)
                    a = __builtin_amdgcn_mfma_f32_16x16x32_bf16(qf[rt][kk], kf[ct][kk], a, 0, 0, 0);
                sc[rt][ct] = a;
            }
        const float scale = 0.08838834764831845f;  // 1/sqrt(128)
        #pragma unroll
        for (int rt = 0; rt < 2; ++rt) {
            #pragma unroll
            for (int r = 0; r < 4; ++r) {
                float x0 = sc[rt][0][r] * scale;
                float x1 = sc[rt][1][r] * scale;
                if (s0 + li >= L) x0 = -1e30f;
                if (s0 + 16 + li >= L) x1 = -1e30f;
                float mx = fmaxf(x0, x1);
                #pragma unroll
                for (int off = 1; off < 16; off <<= 1) mx = fmaxf(mx, __shfl_xor(mx, off, 64));
                float mnew = fmaxf(m_r[rt][r], mx);
                float corr = __expf(m_r[rt][r] - mnew);
                float p0 = __expf(x0 - mnew);
                float p1 = __expf(x1 - mnew);
                float rs = p0 + p1;
                #pragma unroll
                for (int off = 1; off < 16; off <<= 1) rs += __shfl_xor(rs, off, 64);
                m_r[rt][r] = mnew;
                l_r[rt][r] = l_r[rt][r] * corr + rs;
                #pragma unroll
                for (int ht = 0; ht < 8; ++ht) o[rt][ht][r] *= corr;
                Plds[wave][rt * 16 + lg * 4 + r][li]      = __float2bfloat16(p0);
                Plds[wave][rt * 16 + lg * 4 + r][16 + li] = __float2bfloat16(p1);
            }
        }
        asm volatile("s_waitcnt lgkmcnt(0)" ::: "memory");
        bf16x8 pf[2];
        pf[0] = *(const bf16x8*)(&Plds[wave][li][lg * 8]);
        pf[1] = *(const bf16x8*)(&Plds[wave][16 + li][lg * 8]);
        #pragma unroll
        for (int ht = 0; ht < 8; ++ht) {
            bf16x8 vf;
            #pragma unroll
            for (int j = 0; j < 8; ++j) {
                int s = s0 + lg * 8 + j;
                if (s < sp) {
                    vf[j] = f2b(vc[(((size_t)b * MAXS_ + s) * H_ + h) * HD_ + ht * 16 + li]);
                } else if (s < L) {
                    vf[j] = *reinterpret_cast<const short*>(&vb[((size_t)(b * T_ + s - sp) * H_ + h) * HD_ + ht * 16 + li]);
                } else {
                    vf[j] = 0;
                }
            }
            #pragma unroll
            for (int rt = 0; rt < 2; ++rt)
                o[rt][ht] = __builtin_amdgcn_mfma_f32_16x16x32_bf16(pf[rt], vf, o[rt][ht], 0, 0, 0);
        }
    }

    if (li == 0) {
        #pragma unroll
        for (int rt = 0; rt < 2; ++rt)
            for (int r = 0; r < 4; ++r) {
                msh[wave][rt * 16 + lg * 4 + r] = m_r[rt][r];
                lsh[wave][rt * 16 + lg * 4 + r] = l_r[rt][r];
            }
    }
    __syncthreads();
    float corr2[2][4];
    #pragma unroll
    for (int rt = 0; rt < 2; ++rt)
        for (int r = 0; r < 4; ++r) {
            int row = rt * 16 + lg * 4 + r;
            float M = fmaxf(fmaxf(msh[0][row], msh[1][row]), fmaxf(msh[2][row], msh[3][row]));
            corr2[rt][r] = __expf(m_r[rt][r] - M);
        }
    if (tid < 32) {
        int row = tid;
        float M = fmaxf(fmaxf(msh[0][row], msh[1][row]), fmaxf(msh[2][row], msh[3][row]));
        float lt = 0.f;
        #pragma unroll
        for (int w = 0; w < 4; ++w) lt += lsh[w][row] * __expf(msh[w][row] - M);
        ltot[row] = lt;
    }
    for (int w = 0; w < 4; ++w) {
        if (wave == w) {
            #pragma unroll
            for (int rt = 0; rt < 2; ++rt)
                for (int ht = 0; ht < 8; ++ht)
                    for (int r = 0; r < 4; ++r) {
                        int row = rt * 16 + lg * 4 + r, col = ht * 16 + li;
                        float val = o[rt][ht][r] * corr2[rt][r];
                        if (w == 0) Osh[row][col] = val;
                        else Osh[row][col] += val;
                    }
        }
        __syncthreads();
    }
    {
        int row = tid >> 3;
        int c0 = (tid & 7) * 16;
        float inv = 1.0f / ltot[row];
        #pragma unroll
        for (int j = 0; j < 16; ++j)
            ob[(size_t)(b * T_ + row) * D_ + h * HD_ + c0 + j] = __float2bfloat16(Osh[row][c0 + j] * inv);
    }
}

extern "C" void kernel_launch(void* const* d_in, const int* in_sizes, int n_in,
                              void* d_out, int out_size, void* d_ws, size_t ws_size,
                              hipStream_t stream) {
    const float* x  = (const float*)d_in[0];
    const float* wq = (const float*)d_in[1];
    const float* wk = (const float*)d_in[2];
    const float* wv = (const float*)d_in[3];
    const float* wo = (const float*)d_in[4];
    const float* kc = (const float*)d_in[5];
    const float* vc = (const float*)d_in[6];
    const int*   sp = (const int*)d_in[7];

    char* ws = (char*)d_ws;
    const size_t MT = (size_t)M_ * D_;                 // 2M elements
    bf16* wt = (bf16*)ws;                              // [16384][4096] bf16 = 128 MiB (q,k,v,o transposed)
    bf16* xb = (bf16*)(ws + (size_t)4 * D_ * D_ * 2);  // 4 MB each below
    bf16* qb = xb + MT;
    bf16* kb = qb + MT;
    bf16* vb = kb + MT;
    bf16* ab = vb + MT;

    conv_x<<<dim3((int)(MT / 8 / 256)), 256, 0, stream>>>(x, xb);
    transpose_w<<<dim3(64, 64, 4), 256, 0, stream>>>(wq, wk, wv, wo, wt);
    // QKV: N = 12288 (rows 0..12287 of wt), writes qb,kb,vb (bf16)
    gemm_bf16t<128, 0><<<dim3(96, 4), 256, 0, stream>>>(xb, wt, qb);
    rope_inplace<<<dim3((int)(MT / 8 / 256)), 256, 0, stream>>>(qb, kb);
    attn<<<dim3(B_ * H_), 256, 0, stream>>>(qb, kb, vb, kc, vc, sp, ab);
    // wo: rows 12288..16383 of wt, f32 out
    gemm_bf16t<64, 1><<<dim3(32, 8), 256, 0, stream>>>(ab, wt + (size_t)3 * D_ * D_, (float*)d_out);
}

// Round 3
// 509.894 us; speedup vs baseline: 1.6604x; 1.0431x over previous
//
#include <hip/hip_runtime.h>
#include <hip/hip_bf16.h>

#define B_ 16
#define T_ 32
#define D_ 4096
#define H_ 32
#define HD_ 128
#define MAXS_ 2048
#define M_ (B_*T_)   // 512 rows

typedef __hip_bfloat16 bf16;
typedef __attribute__((ext_vector_type(8))) short bf16x8;
typedef __attribute__((ext_vector_type(4))) float f32x4;

static __device__ __forceinline__ short f2b(float f) {
    bf16 h = __float2bfloat16(f);
    return *reinterpret_cast<short*>(&h);
}
static __device__ __forceinline__ float b2f(short s) {
    bf16 h;
    *reinterpret_cast<short*>(&h) = s;
    return __bfloat162float(h);
}

// async global->LDS, 16B per lane; LDS dest is wave-uniform base + lane*16
#define GLD16(gsrc, ldst) \
    __builtin_amdgcn_global_load_lds((const __attribute__((address_space(1))) void*)(gsrc), \
        (__attribute__((address_space(3))) void*)(ldst), 16, 0, 0)

// ---------------- x f32 -> bf16 ----------------
__global__ __launch_bounds__(256) void conv_x(const float* __restrict__ x, bf16* __restrict__ xb) {
    int idx = blockIdx.x * 256 + threadIdx.x;   // 8-element unit
    const float4* xf = (const float4*)x;
    float4 a = xf[idx * 2], b = xf[idx * 2 + 1];
    bf16x8 o;
    o[0] = f2b(a.x); o[1] = f2b(a.y); o[2] = f2b(a.z); o[3] = f2b(a.w);
    o[4] = f2b(b.x); o[5] = f2b(b.y); o[6] = f2b(b.z); o[7] = f2b(b.w);
    *(bf16x8*)&xb[(size_t)idx * 8] = o;
}

// ---------------- W [k][n] f32 -> Wt [n][k] bf16, 64x64 LDS tiles ----------------
__global__ __launch_bounds__(256) void transpose_w(const float* __restrict__ wq,
        const float* __restrict__ wk, const float* __restrict__ wv,
        const float* __restrict__ wo, bf16* __restrict__ wt) {
    __shared__ float Ts[64][65];   // +1 pad: banks rotate per row
    const int bz = blockIdx.z;
    const float* W = (bz == 0) ? wq : (bz == 1) ? wk : (bz == 2) ? wv : wo;
    const int n0 = blockIdx.x * 64, k0 = blockIdx.y * 64;
    const int t = threadIdx.x;
    {
        int kk = t >> 4, nn = (t & 15) * 4;
        #pragma unroll
        for (int r = 0; r < 4; ++r) {
            float4 v = *(const float4*)&W[(size_t)(k0 + kk + 16 * r) * D_ + n0 + nn];
            Ts[kk + 16 * r][nn + 0] = v.x;
            Ts[kk + 16 * r][nn + 1] = v.y;
            Ts[kk + 16 * r][nn + 2] = v.z;
            Ts[kk + 16 * r][nn + 3] = v.w;
        }
    }
    __syncthreads();
    bf16* dst = wt + (size_t)bz * D_ * D_;   // row block bz*4096
    const int kg = t & 7, nr = t >> 3;
    #pragma unroll
    for (int r = 0; r < 2; ++r) {
        int n = nr + 32 * r;
        bf16x8 o;
        #pragma unroll
        for (int j = 0; j < 8; ++j) o[j] = f2b(Ts[kg * 8 + j][n]);
        *(bf16x8*)&dst[(size_t)(n0 + n) * D_ + k0 + kg * 8] = o;
    }
}

// ---------------- bf16 GEMM, m97 structure: gload_lds(16B) + XOR-swizzled LDS ----------------
template<int BM, int MODE>
__global__ __launch_bounds__(256) void gemm_bf16t(const bf16* __restrict__ A,
        const bf16* __restrict__ Bt, void* __restrict__ Cout) {
    constexpr int IM = BM / 32;          // A-frags per wave (wave tile BM/2 x 64)
    constexpr int nA = (BM * 64) / 4096; // gload_lds instrs for A tile
    const int K = D_;
    __shared__ bf16 As[BM * 32];
    __shared__ bf16 Bs[128 * 32];
    const int tid = threadIdx.x, lane = tid & 63, wave = tid >> 6;
    const int wr = wave >> 1, wc = wave & 1;
    const int lg = lane >> 4, li = lane & 15;
    const int row0 = blockIdx.y * BM, col0 = blockIdx.x * 128;
    f32x4 acc[IM][4];
    #pragma unroll
    for (int i = 0; i < IM; ++i)
        #pragma unroll
        for (int j = 0; j < 4; ++j)
            #pragma unroll
            for (int r = 0; r < 4; ++r) acc[i][j][r] = 0.f;

    const int sw = (li & 3) << 4;
    for (int k0 = 0; k0 < K; k0 += 32) {
        #pragma unroll
        for (int i = 0; i < nA; ++i) {
            int X = (i * 256 + tid) * 16;              // linear LDS byte
            int row = X >> 6;
            int kb = (X & 63) ^ ((row & 3) << 4);      // inverse swizzle on source
            GLD16(A + (size_t)(row0 + row) * K + k0 + (kb >> 1),
                  (char*)As + (i * 256 + wave * 64) * 16);
        }
        #pragma unroll
        for (int i = 0; i < 2; ++i) {
            int X = (i * 256 + tid) * 16;
            int row = X >> 6;
            int kb = (X & 63) ^ ((row & 3) << 4);
            GLD16(Bt + (size_t)(col0 + row) * K + k0 + (kb >> 1),
                  (char*)Bs + (i * 256 + wave * 64) * 16);
        }
        __syncthreads();
        bf16x8 af[IM], bfr[4];
        #pragma unroll
        for (int i = 0; i < IM; ++i) {
            int row = wr * (BM / 2) + i * 16 + li;
            af[i] = *(const bf16x8*)((const char*)As + row * 64 + ((lg * 16) ^ sw));
        }
        #pragma unroll
        for (int j = 0; j < 4; ++j) {
            int row = wc * 64 + j * 16 + li;
            bfr[j] = *(const bf16x8*)((const char*)Bs + row * 64 + ((lg * 16) ^ sw));
        }
        #pragma unroll
        for (int i = 0; i < IM; ++i)
            #pragma unroll
            for (int j = 0; j < 4; ++j)
                acc[i][j] = __builtin_amdgcn_mfma_f32_16x16x32_bf16(af[i], bfr[j], acc[i][j], 0, 0, 0);
        __syncthreads();
    }
    if (MODE == 0) {
        bf16* Ob = (bf16*)Cout + (size_t)(col0 >> 12) * M_ * D_;
        const int lcol0 = col0 & (D_ - 1);
        #pragma unroll
        for (int i = 0; i < IM; ++i)
            for (int j = 0; j < 4; ++j)
                for (int r = 0; r < 4; ++r) {
                    int row = row0 + wr * (BM / 2) + i * 16 + lg * 4 + r;
                    int col = lcol0 + wc * 64 + j * 16 + li;
                    Ob[(size_t)row * D_ + col] = __float2bfloat16(acc[i][j][r]);
                }
    } else {
        float* O = (float*)Cout;
        #pragma unroll
        for (int i = 0; i < IM; ++i)
            for (int j = 0; j < 4; ++j)
                for (int r = 0; r < 4; ++r) {
                    int row = row0 + wr * (BM / 2) + i * 16 + lg * 4 + r;
                    int col = col0 + wc * 64 + j * 16 + li;
                    O[(size_t)row * D_ + col] = acc[i][j][r];
                }
    }
}

// ---------------- RoPE in-place on bf16 q,k ----------------
__global__ __launch_bounds__(256) void rope_inplace(bf16* __restrict__ qb, bf16* __restrict__ kb) {
    int idx = blockIdx.x * 256 + threadIdx.x;   // 8-element (4-pair) unit
    size_t e0 = (size_t)idx * 8;
    int hd0 = (int)(e0 & 127);
    int t = (int)((e0 >> 12) & 31);
    bf16x8 q = *(bf16x8*)&qb[e0];
    bf16x8 k = *(bf16x8*)&kb[e0];
    bf16x8 qo, ko;
    #pragma unroll
    for (int p = 0; p < 4; ++p) {
        int i = (hd0 >> 1) + p;
        float theta = exp2f(-(float)i * 0.41524101186092787f);  // log2(10000)/32
        float s, c;
        sincosf((float)t * theta, &s, &c);
        float q0 = b2f(q[2 * p]), q1 = b2f(q[2 * p + 1]);
        qo[2 * p]     = f2b(q0 * c - q1 * s);
        qo[2 * p + 1] = f2b(q1 * c + q0 * s);
        float k0 = b2f(k[2 * p]), k1 = b2f(k[2 * p + 1]);
        ko[2 * p]     = f2b(k0 * c - k1 * s);
        ko[2 * p + 1] = f2b(k1 * c + k0 * s);
    }
    *(bf16x8*)&qb[e0] = qo;
    *(bf16x8*)&kb[e0] = ko;
}

// ---------------- Build per-(b,h) contiguous bf16 K and transposed V ----------------
// Kb: [b][h][s<=2048][128] bf16   (hd-contiguous, QK^T B-operand)
// Vt: [b][h][128][s<=2048] bf16   (s-contiguous, PV B-operand)
// Sources: s<sp from f32 caches; sp<=s<L from fresh roped kb / vb; s>=L untouched (masked downstream).
__global__ __launch_bounds__(256) void conv_kv(const float* __restrict__ kc,
        const float* __restrict__ vc, const bf16* __restrict__ kb,
        const bf16* __restrict__ vb, const int* __restrict__ spp,
        bf16* __restrict__ Kb, bf16* __restrict__ Vt) {
    const int bh = blockIdx.x, b = bh >> 5, h = bh & 31;
    const int s0 = blockIdx.y << 5;
    const int sp = *spp, L = sp + T_;
    if (s0 >= L) return;                  // block-uniform
    __shared__ short Vs[32][136];         // 272B row stride: 16B-aligned, 2-way max conflict
    const int tid = threadIdx.x;
    const int sr = tid >> 3, hq = (tid & 7) << 4;
    const int s = s0 + sr;
    bf16x8 kv0, kv1, vv0, vv1;
    if (s < sp) {
        const float4* kp = (const float4*)&kc[(((size_t)b * MAXS_ + s) * H_ + h) * HD_ + hq];
        const float4* vp = (const float4*)&vc[(((size_t)b * MAXS_ + s) * H_ + h) * HD_ + hq];
        float4 a0 = kp[0], a1 = kp[1], a2 = kp[2], a3 = kp[3];
        kv0[0] = f2b(a0.x); kv0[1] = f2b(a0.y); kv0[2] = f2b(a0.z); kv0[3] = f2b(a0.w);
        kv0[4] = f2b(a1.x); kv0[5] = f2b(a1.y); kv0[6] = f2b(a1.z); kv0[7] = f2b(a1.w);
        kv1[0] = f2b(a2.x); kv1[1] = f2b(a2.y); kv1[2] = f2b(a2.z); kv1[3] = f2b(a2.w);
        kv1[4] = f2b(a3.x); kv1[5] = f2b(a3.y); kv1[6] = f2b(a3.z); kv1[7] = f2b(a3.w);
        float4 c0 = vp[0], c1 = vp[1], c2 = vp[2], c3 = vp[3];
        vv0[0] = f2b(c0.x); vv0[1] = f2b(c0.y); vv0[2] = f2b(c0.z); vv0[3] = f2b(c0.w);
        vv0[4] = f2b(c1.x); vv0[5] = f2b(c1.y); vv0[6] = f2b(c1.z); vv0[7] = f2b(c1.w);
        vv1[0] = f2b(c2.x); vv1[1] = f2b(c2.y); vv1[2] = f2b(c2.z); vv1[3] = f2b(c2.w);
        vv1[4] = f2b(c3.x); vv1[5] = f2b(c3.y); vv1[6] = f2b(c3.z); vv1[7] = f2b(c3.w);
    } else if (s < L) {
        const bf16x8* kp = (const bf16x8*)&kb[(((size_t)b * T_ + (s - sp)) * H_ + h) * HD_ + hq];
        const bf16x8* vp = (const bf16x8*)&vb[(((size_t)b * T_ + (s - sp)) * H_ + h) * HD_ + hq];
        kv0 = kp[0]; kv1 = kp[1];
        vv0 = vp[0]; vv1 = vp[1];
    } else {
        #pragma unroll
        for (int j = 0; j < 8; ++j) { kv0[j] = 0; kv1[j] = 0; vv0[j] = 0; vv1[j] = 0; }
    }
    *(bf16x8*)&Kb[((size_t)bh * MAXS_ + s) * HD_ + hq]     = kv0;
    *(bf16x8*)&Kb[((size_t)bh * MAXS_ + s) * HD_ + hq + 8] = kv1;
    *(bf16x8*)&Vs[sr][hq]     = vv0;
    *(bf16x8*)&Vs[sr][hq + 8] = vv1;
    __syncthreads();
    const int hd = tid >> 1, sc = (tid & 1) << 4;
    bf16x8 o0, o1;
    #pragma unroll
    for (int j = 0; j < 8; ++j) {
        o0[j] = Vs[sc + j][hd];
        o1[j] = Vs[sc + 8 + j][hd];
    }
    *(bf16x8*)&Vt[((size_t)bh * HD_ + hd) * MAXS_ + s0 + sc]     = o0;
    *(bf16x8*)&Vt[((size_t)bh * HD_ + hd) * MAXS_ + s0 + sc + 8] = o1;
}

// ---------------- Flash attention: pure bf16x8 vector loads ----------------
__global__ __launch_bounds__(256) void attn(const bf16* __restrict__ qb,
        const bf16* __restrict__ Kb, const bf16* __restrict__ Vt,
        const int* __restrict__ spp, bf16* __restrict__ ob) {
    const int bh = blockIdx.x;
    const int b = bh >> 5, h = bh & 31;
    const int sp = *spp;
    const int L = sp + T_;
    const int tid = threadIdx.x, lane = tid & 63, wave = tid >> 6;
    const int lg = lane >> 4, li = lane & 15;
    __shared__ bf16 Plds[4][32][40];
    __shared__ float Osh[32][128];
    __shared__ float msh[4][32], lsh[4][32], ltot[32];

    const bf16* Kbase = Kb + (size_t)bh * MAXS_ * HD_;
    const bf16* Vbase = Vt + (size_t)bh * HD_ * MAXS_;

    bf16x8 qf[2][4];
    #pragma unroll
    for (int rt = 0; rt < 2; ++rt)
        #pragma unroll
        for (int kk = 0; kk < 4; ++kk)
            qf[rt][kk] = *(const bf16x8*)(&qb[((size_t)(b * T_ + rt * 16 + li) * H_ + h) * HD_ + kk * 32 + lg * 8]);

    f32x4 o[2][8];
    float m_r[2][4], l_r[2][4];
    #pragma unroll
    for (int rt = 0; rt < 2; ++rt)
        for (int r = 0; r < 4; ++r) { m_r[rt][r] = -1e30f; l_r[rt][r] = 0.f; }
    #pragma unroll
    for (int rt = 0; rt < 2; ++rt) for (int ht = 0; ht < 8; ++ht) for (int r = 0; r < 4; ++r) o[rt][ht][r] = 0.f;

    const int nch = (L + 31) >> 5;
    for (int c = wave; c < nch; c += 4) {
        const int s0 = c * 32;
        bf16x8 kf[2][4];
        #pragma unroll
        for (int ct = 0; ct < 2; ++ct) {
            const bf16* kp = Kbase + (size_t)(s0 + ct * 16 + li) * HD_ + lg * 8;
            #pragma unroll
            for (int kk = 0; kk < 4; ++kk)
                kf[ct][kk] = *(const bf16x8*)(kp + kk * 32);
        }
        f32x4 sc[2][2];
        #pragma unroll
        for (int rt = 0; rt < 2; ++rt)
            #pragma unroll
            for (int ct = 0; ct < 2; ++ct) {
                f32x4 a;
                for (int r = 0; r < 4; ++r) a[r] = 0.f;
                #pragma unroll
                for (int kk = 0; kk < 4; ++kk)
                    a = __builtin_amdgcn_mfma_f32_16x16x32_bf16(qf[rt][kk], kf[ct][kk], a, 0, 0, 0);
                sc[rt][ct] = a;
            }
        const float scale = 0.08838834764831845f;  // 1/sqrt(128)
        #pragma unroll
        for (int rt = 0; rt < 2; ++rt) {
            #pragma unroll
            for (int r = 0; r < 4; ++r) {
                float x0 = sc[rt][0][r] * scale;
                float x1 = sc[rt][1][r] * scale;
                if (s0 + li >= L) x0 = -1e30f;
                if (s0 + 16 + li >= L) x1 = -1e30f;
                float mx = fmaxf(x0, x1);
                #pragma unroll
                for (int off = 1; off < 16; off <<= 1) mx = fmaxf(mx, __shfl_xor(mx, off, 64));
                float mnew = fmaxf(m_r[rt][r], mx);
                float corr = __expf(m_r[rt][r] - mnew);
                float p0 = __expf(x0 - mnew);
                float p1 = __expf(x1 - mnew);
                float rs = p0 + p1;
                #pragma unroll
                for (int off = 1; off < 16; off <<= 1) rs += __shfl_xor(rs, off, 64);
                m_r[rt][r] = mnew;
                l_r[rt][r] = l_r[rt][r] * corr + rs;
                #pragma unroll
                for (int ht = 0; ht < 8; ++ht) o[rt][ht][r] *= corr;
                Plds[wave][rt * 16 + lg * 4 + r][li]      = __float2bfloat16(p0);
                Plds[wave][rt * 16 + lg * 4 + r][16 + li] = __float2bfloat16(p1);
            }
        }
        asm volatile("s_waitcnt lgkmcnt(0)" ::: "memory");
        bf16x8 pf[2];
        pf[0] = *(const bf16x8*)(&Plds[wave][li][lg * 8]);
        pf[1] = *(const bf16x8*)(&Plds[wave][16 + li][lg * 8]);
        #pragma unroll
        for (int ht = 0; ht < 8; ++ht) {
            bf16x8 vf = *(const bf16x8*)(Vbase + (size_t)(ht * 16 + li) * MAXS_ + s0 + lg * 8);
            #pragma unroll
            for (int rt = 0; rt < 2; ++rt)
                o[rt][ht] = __builtin_amdgcn_mfma_f32_16x16x32_bf16(pf[rt], vf, o[rt][ht], 0, 0, 0);
        }
    }

    if (li == 0) {
        #pragma unroll
        for (int rt = 0; rt < 2; ++rt)
            for (int r = 0; r < 4; ++r) {
                msh[wave][rt * 16 + lg * 4 + r] = m_r[rt][r];
                lsh[wave][rt * 16 + lg * 4 + r] = l_r[rt][r];
            }
    }
    __syncthreads();
    float corr2[2][4];
    #pragma unroll
    for (int rt = 0; rt < 2; ++rt)
        for (int r = 0; r < 4; ++r) {
            int row = rt * 16 + lg * 4 + r;
            float M = fmaxf(fmaxf(msh[0][row], msh[1][row]), fmaxf(msh[2][row], msh[3][row]));
            corr2[rt][r] = __expf(m_r[rt][r] - M);
        }
    if (tid < 32) {
        int row = tid;
        float M = fmaxf(fmaxf(msh[0][row], msh[1][row]), fmaxf(msh[2][row], msh[3][row]));
        float lt = 0.f;
        #pragma unroll
        for (int w = 0; w < 4; ++w) lt += lsh[w][row] * __expf(msh[w][row] - M);
        ltot[row] = lt;
    }
    for (int w = 0; w < 4; ++w) {
        if (wave == w) {
            #pragma unroll
            for (int rt = 0; rt < 2; ++rt)
                for (int ht = 0; ht < 8; ++ht)
                    for (int r = 0; r < 4; ++r) {
                        int row = rt * 16 + lg * 4 + r, col = ht * 16 + li;
                        float val = o[rt][ht][r] * corr2[rt][r];
                        if (w == 0) Osh[row][col] = val;
                        else Osh[row][col] += val;
                    }
        }
        __syncthreads();
    }
    {
        int row = tid >> 3;
        int c0 = (tid & 7) * 16;
        float inv = 1.0f / ltot[row];
        #pragma unroll
        for (int j = 0; j < 16; ++j)
            ob[(size_t)(b * T_ + row) * D_ + h * HD_ + c0 + j] = __float2bfloat16(Osh[row][c0 + j] * inv);
    }
}

extern "C" void kernel_launch(void* const* d_in, const int* in_sizes, int n_in,
                              void* d_out, int out_size, void* d_ws, size_t ws_size,
                              hipStream_t stream) {
    const float* x  = (const float*)d_in[0];
    const float* wq = (const float*)d_in[1];
    const float* wk = (const float*)d_in[2];
    const float* wv = (const float*)d_in[3];
    const float* wo = (const float*)d_in[4];
    const float* kc = (const float*)d_in[5];
    const float* vc = (const float*)d_in[6];
    const int*   sp = (const int*)d_in[7];

    char* ws = (char*)d_ws;
    const size_t MT = (size_t)M_ * D_;                 // 2M elements
    bf16* wt = (bf16*)ws;                              // 128 MiB (wq,wk,wv,wo transposed)
    bf16* xb = wt + (size_t)4 * D_ * D_;
    bf16* qb = xb + MT;
    bf16* kb = qb + MT;
    bf16* vb = kb + MT;
    bf16* ab = vb + MT;
    bf16* Kb = ab + MT;                                // [B*H][2048][128] = 268 MB
    bf16* Vt = Kb + (size_t)B_ * H_ * MAXS_ * HD_;     // [B*H][128][2048] = 268 MB

    conv_x<<<dim3((int)(MT / 8 / 256)), 256, 0, stream>>>(x, xb);
    transpose_w<<<dim3(64, 64, 4), 256, 0, stream>>>(wq, wk, wv, wo, wt);
    gemm_bf16t<128, 0><<<dim3(96, 4), 256, 0, stream>>>(xb, wt, qb);
    rope_inplace<<<dim3((int)(MT / 8 / 256)), 256, 0, stream>>>(qb, kb);
    conv_kv<<<dim3(B_ * H_, MAXS_ / 32), 256, 0, stream>>>(kc, vc, kb, vb, sp, Kb, Vt);
    attn<<<dim3(B_ * H_), 256, 0, stream>>>(qb, Kb, Vt, sp, ab);
    gemm_bf16t<64, 1><<<dim3(32, 8), 256, 0, stream>>>(ab, wt + (size_t)3 * D_ * D_, (float*)d_out);
}

// Round 4
// 475.757 us; speedup vs baseline: 1.7795x; 1.0718x over previous
//
#include <hip/hip_runtime.h>
#include <hip/hip_bf16.h>

#define B_ 16
#define T_ 32
#define D_ 4096
#define H_ 32
#define HD_ 128
#define MAXS_ 2048
#define M_ (B_*T_)   // 512 rows

typedef __hip_bfloat16 bf16;
typedef __attribute__((ext_vector_type(8))) short bf16x8;
typedef __attribute__((ext_vector_type(4))) float f32x4;

static __device__ __forceinline__ short f2b(float f) {
    bf16 h = __float2bfloat16(f);
    return *reinterpret_cast<short*>(&h);
}
static __device__ __forceinline__ float b2f(short s) {
    bf16 h;
    *reinterpret_cast<short*>(&h) = s;
    return __bfloat162float(h);
}

// async global->LDS, 16B per lane; LDS dest is wave-uniform base + lane*16
#define GLD16(gsrc, ldst) \
    __builtin_amdgcn_global_load_lds((const __attribute__((address_space(1))) void*)(gsrc), \
        (__attribute__((address_space(3))) void*)(ldst), 16, 0, 0)

// ---------------- x f32 -> bf16 ----------------
__global__ __launch_bounds__(256) void conv_x(const float* __restrict__ x, bf16* __restrict__ xb) {
    int idx = blockIdx.x * 256 + threadIdx.x;   // 8-element unit
    const float4* xf = (const float4*)x;
    float4 a = xf[idx * 2], b = xf[idx * 2 + 1];
    bf16x8 o;
    o[0] = f2b(a.x); o[1] = f2b(a.y); o[2] = f2b(a.z); o[3] = f2b(a.w);
    o[4] = f2b(b.x); o[5] = f2b(b.y); o[6] = f2b(b.z); o[7] = f2b(b.w);
    *(bf16x8*)&xb[(size_t)idx * 8] = o;
}

// ---------------- W [k][n] f32 -> Wt [n][k] bf16, 64x64 LDS tiles ----------------
__global__ __launch_bounds__(256) void transpose_w(const float* __restrict__ wq,
        const float* __restrict__ wk, const float* __restrict__ wv,
        const float* __restrict__ wo, bf16* __restrict__ wt) {
    __shared__ float Ts[64][65];   // +1 pad: banks rotate per row
    const int bz = blockIdx.z;
    const float* W = (bz == 0) ? wq : (bz == 1) ? wk : (bz == 2) ? wv : wo;
    const int n0 = blockIdx.x * 64, k0 = blockIdx.y * 64;
    const int t = threadIdx.x;
    {
        int kk = t >> 4, nn = (t & 15) * 4;
        #pragma unroll
        for (int r = 0; r < 4; ++r) {
            float4 v = *(const float4*)&W[(size_t)(k0 + kk + 16 * r) * D_ + n0 + nn];
            Ts[kk + 16 * r][nn + 0] = v.x;
            Ts[kk + 16 * r][nn + 1] = v.y;
            Ts[kk + 16 * r][nn + 2] = v.z;
            Ts[kk + 16 * r][nn + 3] = v.w;
        }
    }
    __syncthreads();
    bf16* dst = wt + (size_t)bz * D_ * D_;   // row block bz*4096
    const int kg = t & 7, nr = t >> 3;
    #pragma unroll
    for (int r = 0; r < 2; ++r) {
        int n = nr + 32 * r;
        bf16x8 o;
        #pragma unroll
        for (int j = 0; j < 8; ++j) o[j] = f2b(Ts[kg * 8 + j][n]);
        *(bf16x8*)&dst[(size_t)(n0 + n) * D_ + k0 + kg * 8] = o;
    }
}

// ---------------- bf16 GEMM, m97 structure: gload_lds(16B) + XOR-swizzled LDS ----------------
template<int BM, int MODE>
__global__ __launch_bounds__(256) void gemm_bf16t(const bf16* __restrict__ A,
        const bf16* __restrict__ Bt, void* __restrict__ Cout) {
    constexpr int IM = BM / 32;          // A-frags per wave (wave tile BM/2 x 64)
    constexpr int nA = (BM * 64) / 4096; // gload_lds instrs for A tile
    const int K = D_;
    __shared__ bf16 As[BM * 32];
    __shared__ bf16 Bs[128 * 32];
    const int tid = threadIdx.x, lane = tid & 63, wave = tid >> 6;
    const int wr = wave >> 1, wc = wave & 1;
    const int lg = lane >> 4, li = lane & 15;
    const int row0 = blockIdx.y * BM, col0 = blockIdx.x * 128;
    f32x4 acc[IM][4];
    #pragma unroll
    for (int i = 0; i < IM; ++i)
        #pragma unroll
        for (int j = 0; j < 4; ++j)
            #pragma unroll
            for (int r = 0; r < 4; ++r) acc[i][j][r] = 0.f;

    const int sw = (li & 3) << 4;
    for (int k0 = 0; k0 < K; k0 += 32) {
        #pragma unroll
        for (int i = 0; i < nA; ++i) {
            int X = (i * 256 + tid) * 16;              // linear LDS byte
            int row = X >> 6;
            int kb = (X & 63) ^ ((row & 3) << 4);      // inverse swizzle on source
            GLD16(A + (size_t)(row0 + row) * K + k0 + (kb >> 1),
                  (char*)As + (i * 256 + wave * 64) * 16);
        }
        #pragma unroll
        for (int i = 0; i < 2; ++i) {
            int X = (i * 256 + tid) * 16;
            int row = X >> 6;
            int kb = (X & 63) ^ ((row & 3) << 4);
            GLD16(Bt + (size_t)(col0 + row) * K + k0 + (kb >> 1),
                  (char*)Bs + (i * 256 + wave * 64) * 16);
        }
        __syncthreads();
        bf16x8 af[IM], bfr[4];
        #pragma unroll
        for (int i = 0; i < IM; ++i) {
            int row = wr * (BM / 2) + i * 16 + li;
            af[i] = *(const bf16x8*)((const char*)As + row * 64 + ((lg * 16) ^ sw));
        }
        #pragma unroll
        for (int j = 0; j < 4; ++j) {
            int row = wc * 64 + j * 16 + li;
            bfr[j] = *(const bf16x8*)((const char*)Bs + row * 64 + ((lg * 16) ^ sw));
        }
        #pragma unroll
        for (int i = 0; i < IM; ++i)
            #pragma unroll
            for (int j = 0; j < 4; ++j)
                acc[i][j] = __builtin_amdgcn_mfma_f32_16x16x32_bf16(af[i], bfr[j], acc[i][j], 0, 0, 0);
        __syncthreads();
    }
    if (MODE == 0) {
        bf16* Ob = (bf16*)Cout + (size_t)(col0 >> 12) * M_ * D_;
        const int lcol0 = col0 & (D_ - 1);
        #pragma unroll
        for (int i = 0; i < IM; ++i)
            for (int j = 0; j < 4; ++j)
                for (int r = 0; r < 4; ++r) {
                    int row = row0 + wr * (BM / 2) + i * 16 + lg * 4 + r;
                    int col = lcol0 + wc * 64 + j * 16 + li;
                    Ob[(size_t)row * D_ + col] = __float2bfloat16(acc[i][j][r]);
                }
    } else {
        float* O = (float*)Cout;
        #pragma unroll
        for (int i = 0; i < IM; ++i)
            for (int j = 0; j < 4; ++j)
                for (int r = 0; r < 4; ++r) {
                    int row = row0 + wr * (BM / 2) + i * 16 + lg * 4 + r;
                    int col = col0 + wc * 64 + j * 16 + li;
                    O[(size_t)row * D_ + col] = acc[i][j][r];
                }
    }
}

// ---------------- RoPE in-place on bf16 q,k ----------------
__global__ __launch_bounds__(256) void rope_inplace(bf16* __restrict__ qb, bf16* __restrict__ kb) {
    int idx = blockIdx.x * 256 + threadIdx.x;   // 8-element (4-pair) unit
    size_t e0 = (size_t)idx * 8;
    int hd0 = (int)(e0 & 127);
    int t = (int)((e0 >> 12) & 31);
    bf16x8 q = *(bf16x8*)&qb[e0];
    bf16x8 k = *(bf16x8*)&kb[e0];
    bf16x8 qo, ko;
    #pragma unroll
    for (int p = 0; p < 4; ++p) {
        int i = (hd0 >> 1) + p;
        float theta = exp2f(-(float)i * 0.41524101186092787f);  // log2(10000)/32
        float s, c;
        sincosf((float)t * theta, &s, &c);
        float q0 = b2f(q[2 * p]), q1 = b2f(q[2 * p + 1]);
        qo[2 * p]     = f2b(q0 * c - q1 * s);
        qo[2 * p + 1] = f2b(q1 * c + q0 * s);
        float k0 = b2f(k[2 * p]), k1 = b2f(k[2 * p + 1]);
        ko[2 * p]     = f2b(k0 * c - k1 * s);
        ko[2 * p + 1] = f2b(k1 * c + k0 * s);
    }
    *(bf16x8*)&qb[e0] = qo;
    *(bf16x8*)&kb[e0] = ko;
}

// ---------------- Fused flash attention: reads f32 caches + fresh bf16 rows directly ----------------
// 1 block per (b,h); 4 waves round-robin over 32-s chunks; V transposed per-wave in LDS.
__global__ __launch_bounds__(256) void attn(const bf16* __restrict__ qb,
        const bf16* __restrict__ kb, const bf16* __restrict__ vb,
        const float* __restrict__ kc, const float* __restrict__ vc,
        const int* __restrict__ spp, bf16* __restrict__ ob) {
    const int bh = blockIdx.x;
    const int b = bh >> 5, h = bh & 31;
    const int sp = *spp;
    const int L = sp + T_;
    const int tid = threadIdx.x, lane = tid & 63, wave = tid >> 6;
    const int lg = lane >> 4, li = lane & 15;
    __shared__ short Vt[4][128][36];   // per-wave transposed V chunk; stride 72B + XOR swizzle
    __shared__ bf16 Plds[4][32][40];
    __shared__ float Osh[32][128];
    __shared__ float msh[4][32], lsh[4][32], ltot[32];

    bf16x8 qf[2][4];
    #pragma unroll
    for (int rt = 0; rt < 2; ++rt)
        #pragma unroll
        for (int kk = 0; kk < 4; ++kk)
            qf[rt][kk] = *(const bf16x8*)(&qb[((size_t)(b * T_ + rt * 16 + li) * H_ + h) * HD_ + kk * 32 + lg * 8]);

    f32x4 o[2][8];
    float m_r[2][4], l_r[2][4];
    #pragma unroll
    for (int rt = 0; rt < 2; ++rt)
        for (int r = 0; r < 4; ++r) { m_r[rt][r] = -1e30f; l_r[rt][r] = 0.f; }
    #pragma unroll
    for (int rt = 0; rt < 2; ++rt) for (int ht = 0; ht < 8; ++ht) for (int r = 0; r < 4; ++r) o[rt][ht][r] = 0.f;

    const int nch = (L + 31) >> 5;
    for (int c = wave; c < nch; c += 4) {
        const int s0 = c * 32;

        // ---- stage V chunk (32 s x 128 hd) transposed into Vt[wave] ----
        // lane handles two 8s x 4hd blocks; reg transpose; swizzled ds_write_b128
        #pragma unroll
        for (int rep = 0; rep < 2; ++rep) {
            int blk = rep * 64 + lane;
            int a = blk >> 5;            // 0..3 : s octet
            int bq = blk & 31;           // hd quad
            short tv[8][4];
            #pragma unroll
            for (int i = 0; i < 8; ++i) {
                int s = s0 + a * 8 + i;
                if (s < sp) {
                    float4 v = *(const float4*)&vc[(((size_t)b * MAXS_ + s) * H_ + h) * HD_ + bq * 4];
                    tv[i][0] = f2b(v.x); tv[i][1] = f2b(v.y); tv[i][2] = f2b(v.z); tv[i][3] = f2b(v.w);
                } else if (s < L) {
                    ushort4 u = *(const ushort4*)&vb[(((size_t)b * T_ + (s - sp)) * H_ + h) * HD_ + bq * 4];
                    tv[i][0] = (short)u.x; tv[i][1] = (short)u.y; tv[i][2] = (short)u.z; tv[i][3] = (short)u.w;
                } else {
                    tv[i][0] = 0; tv[i][1] = 0; tv[i][2] = 0; tv[i][3] = 0;
                }
            }
            #pragma unroll
            for (int j = 0; j < 4; ++j) {
                int row = bq * 4 + j;
                bf16x8 w;
                #pragma unroll
                for (int i = 0; i < 8; ++i) w[i] = tv[i][j];
                int colB = (a * 16) ^ (((row >> 4) & 3) << 4);
                *(bf16x8*)((char*)&Vt[wave][row][0] + colB) = w;
            }
        }

        // ---- K fragments straight from source (f32 cache / fresh bf16) ----
        bf16x8 kf[2][4];
        #pragma unroll
        for (int ct = 0; ct < 2; ++ct) {
            int s = s0 + ct * 16 + li;
            if (s < sp) {
                const float* kp = &kc[(((size_t)b * MAXS_ + s) * H_ + h) * HD_];
                #pragma unroll
                for (int kk = 0; kk < 4; ++kk) {
                    float4 v0 = *(const float4*)(&kp[kk * 32 + lg * 8]);
                    float4 v1 = *(const float4*)(&kp[kk * 32 + lg * 8 + 4]);
                    bf16x8 f;
                    f[0] = f2b(v0.x); f[1] = f2b(v0.y); f[2] = f2b(v0.z); f[3] = f2b(v0.w);
                    f[4] = f2b(v1.x); f[5] = f2b(v1.y); f[6] = f2b(v1.z); f[7] = f2b(v1.w);
                    kf[ct][kk] = f;
                }
            } else if (s < L) {
                const bf16* kp = &kb[((size_t)(b * T_ + s - sp) * H_ + h) * HD_];
                #pragma unroll
                for (int kk = 0; kk < 4; ++kk)
                    kf[ct][kk] = *(const bf16x8*)(kp + kk * 32 + lg * 8);
            } else {
                #pragma unroll
                for (int kk = 0; kk < 4; ++kk) {
                    bf16x8 f;
                    #pragma unroll
                    for (int j = 0; j < 8; ++j) f[j] = 0;
                    kf[ct][kk] = f;
                }
            }
        }

        // ---- QK^T ----
        f32x4 sc[2][2];
        #pragma unroll
        for (int rt = 0; rt < 2; ++rt)
            #pragma unroll
            for (int ct = 0; ct < 2; ++ct) {
                f32x4 a;
                for (int r = 0; r < 4; ++r) a[r] = 0.f;
                #pragma unroll
                for (int kk = 0; kk < 4; ++kk)
                    a = __builtin_amdgcn_mfma_f32_16x16x32_bf16(qf[rt][kk], kf[ct][kk], a, 0, 0, 0);
                sc[rt][ct] = a;
            }

        // ---- online softmax ----
        const float scale = 0.08838834764831845f;  // 1/sqrt(128)
        #pragma unroll
        for (int rt = 0; rt < 2; ++rt) {
            #pragma unroll
            for (int r = 0; r < 4; ++r) {
                float x0 = sc[rt][0][r] * scale;
                float x1 = sc[rt][1][r] * scale;
                if (s0 + li >= L) x0 = -1e30f;
                if (s0 + 16 + li >= L) x1 = -1e30f;
                float mx = fmaxf(x0, x1);
                #pragma unroll
                for (int off = 1; off < 16; off <<= 1) mx = fmaxf(mx, __shfl_xor(mx, off, 64));
                float mnew = fmaxf(m_r[rt][r], mx);
                float corr = __expf(m_r[rt][r] - mnew);
                float p0 = __expf(x0 - mnew);
                float p1 = __expf(x1 - mnew);
                float rs = p0 + p1;
                #pragma unroll
                for (int off = 1; off < 16; off <<= 1) rs += __shfl_xor(rs, off, 64);
                m_r[rt][r] = mnew;
                l_r[rt][r] = l_r[rt][r] * corr + rs;
                #pragma unroll
                for (int ht = 0; ht < 8; ++ht) o[rt][ht][r] *= corr;
                Plds[wave][rt * 16 + lg * 4 + r][li]      = __float2bfloat16(p0);
                Plds[wave][rt * 16 + lg * 4 + r][16 + li] = __float2bfloat16(p1);
            }
        }

        // drain wave-private LDS writes (Vt + Plds) before cross-lane reads
        asm volatile("s_waitcnt lgkmcnt(0)" ::: "memory");
        bf16x8 pf[2];
        pf[0] = *(const bf16x8*)(&Plds[wave][li][lg * 8]);
        pf[1] = *(const bf16x8*)(&Plds[wave][16 + li][lg * 8]);

        // ---- PV from transposed LDS ----
        #pragma unroll
        for (int ht = 0; ht < 8; ++ht) {
            int row = ht * 16 + li;
            int colB = (lg * 16) ^ ((ht & 3) << 4);
            bf16x8 vf = *(const bf16x8*)((const char*)&Vt[wave][row][0] + colB);
            #pragma unroll
            for (int rt = 0; rt < 2; ++rt)
                o[rt][ht] = __builtin_amdgcn_mfma_f32_16x16x32_bf16(pf[rt], vf, o[rt][ht], 0, 0, 0);
        }
    }

    // ---- cross-wave combine ----
    if (li == 0) {
        #pragma unroll
        for (int rt = 0; rt < 2; ++rt)
            for (int r = 0; r < 4; ++r) {
                msh[wave][rt * 16 + lg * 4 + r] = m_r[rt][r];
                lsh[wave][rt * 16 + lg * 4 + r] = l_r[rt][r];
            }
    }
    __syncthreads();
    float corr2[2][4];
    #pragma unroll
    for (int rt = 0; rt < 2; ++rt)
        for (int r = 0; r < 4; ++r) {
            int row = rt * 16 + lg * 4 + r;
            float M = fmaxf(fmaxf(msh[0][row], msh[1][row]), fmaxf(msh[2][row], msh[3][row]));
            corr2[rt][r] = __expf(m_r[rt][r] - M);
        }
    if (tid < 32) {
        int row = tid;
        float M = fmaxf(fmaxf(msh[0][row], msh[1][row]), fmaxf(msh[2][row], msh[3][row]));
        float lt = 0.f;
        #pragma unroll
        for (int w = 0; w < 4; ++w) lt += lsh[w][row] * __expf(msh[w][row] - M);
        ltot[row] = lt;
    }
    for (int w = 0; w < 4; ++w) {
        if (wave == w) {
            #pragma unroll
            for (int rt = 0; rt < 2; ++rt)
                for (int ht = 0; ht < 8; ++ht)
                    for (int r = 0; r < 4; ++r) {
                        int row = rt * 16 + lg * 4 + r, col = ht * 16 + li;
                        float val = o[rt][ht][r] * corr2[rt][r];
                        if (w == 0) Osh[row][col] = val;
                        else Osh[row][col] += val;
                    }
        }
        __syncthreads();
    }
    {
        int row = tid >> 3;
        int c0 = (tid & 7) * 16;
        float inv = 1.0f / ltot[row];
        #pragma unroll
        for (int j = 0; j < 16; ++j)
            ob[(size_t)(b * T_ + row) * D_ + h * HD_ + c0 + j] = __float2bfloat16(Osh[row][c0 + j] * inv);
    }
}

extern "C" void kernel_launch(void* const* d_in, const int* in_sizes, int n_in,
                              void* d_out, int out_size, void* d_ws, size_t ws_size,
                              hipStream_t stream) {
    const float* x  = (const float*)d_in[0];
    const float* wq = (const float*)d_in[1];
    const float* wk = (const float*)d_in[2];
    const float* wv = (const float*)d_in[3];
    const float* wo = (const float*)d_in[4];
    const float* kc = (const float*)d_in[5];
    const float* vc = (const float*)d_in[6];
    const int*   sp = (const int*)d_in[7];

    char* ws = (char*)d_ws;
    const size_t MT = (size_t)M_ * D_;                 // 2M elements
    bf16* wt = (bf16*)ws;                              // 128 MiB (wq,wk,wv,wo transposed)
    bf16* xb = wt + (size_t)4 * D_ * D_;
    bf16* qb = xb + MT;
    bf16* kb = qb + MT;
    bf16* vb = kb + MT;
    bf16* ab = vb + MT;

    conv_x<<<dim3((int)(MT / 8 / 256)), 256, 0, stream>>>(x, xb);
    transpose_w<<<dim3(64, 64, 4), 256, 0, stream>>>(wq, wk, wv, wo, wt);
    gemm_bf16t<128, 0><<<dim3(96, 4), 256, 0, stream>>>(xb, wt, qb);
    rope_inplace<<<dim3((int)(MT / 8 / 256)), 256, 0, stream>>>(qb, kb);
    attn<<<dim3(B_ * H_), 256, 0, stream>>>(qb, kb, vb, kc, vc, sp, ab);
    gemm_bf16t<64, 1><<<dim3(32, 8), 256, 0, stream>>>(ab, wt + (size_t)3 * D_ * D_, (float*)d_out);
}